// Round 13
// baseline (2486.715 us; speedup 1.0000x reference)
//
#include <hip/hip_runtime.h>
#include <stdint.h>

typedef _Float16 h16;
typedef __attribute__((ext_vector_type(8))) _Float16 f16x8;
typedef __attribute__((ext_vector_type(4))) float f32x4;

// Problem: B=8, T=2048, D=1024, NODES=1024  (fp32 in/out)
//
// Shared ws prefix (both paths):
//   Xh  @ 0         : 33554432   (X fp16)            -- dead after qkv
//   Wt  @ 33554432  : 6291456    (W^T fp16 [n][d])   -- dead after qkv
//   Vt  @ 39845888  : 33554432   (V^T fp16 [b][n][t])-- live to end
// BIG path (ws >= 144703488): flat chain, S stored fp16 relative to seg-max:
//   S16 @ 73400320  : 67108864   ([b][row][2048] h16 = s - m_seg; P in-place)
//   Smax@ 140509184 : 4194304    ([b][row][64] f32 per-32col-seg max)
//   chain: conv, qkv256, S_all(512), SM_all(16384), O_all(256)
// GEMM core: 256x256 8-phase, BK=32, 64 KiB LDS -> 2 blocks/CU (r13 change).
// SMALL path (fallback): r10 group-of-2 pairing chain.
// Q,K fp16 live in d_out per-batch [Q_b|K_b] 8 MiB; O_b fp32 overwrites it.

#define GLD16(gsrc, ldst)                                                     \
    __builtin_amdgcn_global_load_lds(                                         \
        (const __attribute__((address_space(1))) uint32_t*)(gsrc),            \
        (__attribute__((address_space(3))) uint32_t*)(ldst), 16, 0, 0)

#define FENCE asm volatile("" ::: "memory")
#define BARRIER do { FENCE; __builtin_amdgcn_s_barrier(); FENCE; } while (0)
#define LGKM0  asm volatile("s_waitcnt lgkmcnt(0)" ::: "memory")
#define VMCNT2 asm volatile("s_waitcnt vmcnt(2)" ::: "memory")
#define VMCNT0 asm volatile("s_waitcnt vmcnt(0)" ::: "memory")

// ---------------- merged conversion kernel ----------------
__global__ __launch_bounds__(256) void k_conv(const float* __restrict__ X,
                                              h16* __restrict__ Xh,
                                              const float* __restrict__ W0,
                                              const float* __restrict__ W1,
                                              const float* __restrict__ W2,
                                              h16* __restrict__ Wt) {
    __shared__ h16 LT[64 * 72];
    int t = threadIdx.x;
    if (blockIdx.x < 8192) {
        size_t i = ((size_t)blockIdx.x * 256 + t) * 8;
        f32x4 a = *(const f32x4*)(X + i);
        f32x4 b = *(const f32x4*)(X + i + 4);
        f16x8 o;
        o[0] = (h16)a[0]; o[1] = (h16)a[1]; o[2] = (h16)a[2]; o[3] = (h16)a[3];
        o[4] = (h16)b[0]; o[5] = (h16)b[1]; o[6] = (h16)b[2]; o[7] = (h16)b[3];
        *(f16x8*)(Xh + i) = o;
        return;
    }
    int bid2 = blockIdx.x - 8192;
    int which = bid2 >> 8;
    int tile  = bid2 & 255;
    int d0 = (tile >> 4) * 64, n0 = (tile & 15) * 64;
    const float* W = (which == 0) ? W0 : ((which == 1) ? W1 : W2);
    h16* dst = Wt + (size_t)which * (1024 * 1024);
#pragma unroll
    for (int p = 0; p < 4; ++p) {
        int c = t + p * 256;
        int r = c >> 4;
        int cf = (c & 15) * 4;
        f32x4 v = *(const f32x4*)&W[(size_t)(d0 + r) * 1024 + n0 + cf];
#pragma unroll
        for (int e = 0; e < 4; ++e) LT[(cf + e) * 72 + r] = (h16)v[e];
    }
    __syncthreads();
#pragma unroll
    for (int p = 0; p < 2; ++p) {
        int q = t + p * 256;
        int nl = q >> 3;
        int dc = (q & 7) * 8;
        f16x8 v = *(f16x8*)&LT[nl * 72 + dc];
        *(f16x8*)&dst[(size_t)(n0 + nl) * 1024 + d0 + dc] = v;
    }
}

// ===== 256x256 8-phase core, BK=32, 64 KiB LDS (2 blocks/CU) =====
// Locals required: smem, t, loff, sw, A, Bt, rowBase, nc0, wr, wc, fr, kq,
//                  acc, a, b, compile-time-const size_t ldab.
// LDS: A @ buf*16384, B @ 32768 + buf*16384; tile 256 rows x 4 slots of 16B;
// physical slot = logical slot ^ (row&3); staged via inverse-swizzled global
// source + linear global_load_lds dest (one GLD16 per thread per stage-op).
#define STAGE_OP(OPREG, OPPTR, OPROW, BUF, H, KT) do {                          \
        const h16* _src = (OPPTR) + (size_t)((OPROW) + (H) * 128 + (t >> 2)) * ldab \
                          + (KT) * 32 + loff;                                   \
        char* _dst = smem + (OPREG) + (BUF) * 16384 + (H) * 8192 + t * 16;      \
        GLD16(_src, _dst);                                                      \
    } while (0)
#define STAGE_A(BUF, H, KT) STAGE_OP(0, A, rowBase, BUF, H, KT)
#define STAGE_B(BUF, H, KT) STAGE_OP(32768, Bt, nc0, BUF, H, KT)

#define RD(REG, ROW, SLOT) \
    (*(const f16x8*)(smem + (REG) + (ROW) * 64 + ((((SLOT)) ^ sw) << 4)))

#define PH(BUF, MH, NH, DOA, STG, VM) do {                                      \
        if (DOA) {                                                              \
            _Pragma("unroll") for (int q = 0; q < 4; ++q)                       \
                a[q] = RD((BUF) * 16384,                                        \
                          (MH) * 128 + wr * 64 + q * 16 + fr, kq);              \
        }                                                                       \
        _Pragma("unroll") for (int nf = 0; nf < 2; ++nf)                        \
            b[nf] = RD(32768 + (BUF) * 16384,                                   \
                       (NH) * 128 + wc * 32 + nf * 16 + fr, kq);                \
        STG;                                                                    \
        VM;                                                                     \
        BARRIER; LGKM0;                                                         \
        __builtin_amdgcn_s_setprio(1);                                          \
        _Pragma("unroll") for (int q = 0; q < 4; ++q)                           \
        _Pragma("unroll") for (int nf = 0; nf < 2; ++nf)                        \
            acc[MH][NH][q][nf] = __builtin_amdgcn_mfma_f32_16x16x32_f16(        \
                a[q], b[nf], acc[MH][NH][q][nf], 0, 0, 0);                      \
        __builtin_amdgcn_s_setprio(0);                                          \
        BARRIER;                                                                \
    } while (0)

// NTT = number of 32-wide K-tiles (power of 2).
#define CORE_LOOP(NTT)                                                          \
    STAGE_A(0, 0, 0); STAGE_A(0, 1, 0);                                         \
    STAGE_B(0, 0, 0); STAGE_B(0, 1, 0);                                         \
    STAGE_A(1, 0, 1); STAGE_B(1, 0, 1);                                         \
    VMCNT2;                                                                     \
    BARRIER;                                                                    \
    for (int i = 0; i < (NTT) / 2; ++i) {                                       \
        const int tb  = 2 * i + 1;                                              \
        const int tc2 = (2 * i + 2) & ((NTT) - 1);                              \
        const int td  = (2 * i + 3) & ((NTT) - 1);                              \
        PH(0, 0, 0, 1, STAGE_A(1, 1, tb),  (void)0);                            \
        PH(0, 0, 1, 0, STAGE_B(1, 1, tb),  (void)0);                            \
        PH(0, 1, 0, 1, STAGE_A(0, 0, tc2), (void)0);                            \
        PH(0, 1, 1, 0, STAGE_B(0, 0, tc2), VMCNT2);                             \
        PH(1, 0, 0, 1, STAGE_A(0, 1, tc2), (void)0);                            \
        PH(1, 0, 1, 0, STAGE_B(0, 1, tc2), (void)0);                            \
        PH(1, 1, 0, 1, STAGE_A(1, 0, td),  (void)0);                            \
        PH(1, 1, 1, 0, STAGE_B(1, 0, td),  VMCNT2);                             \
    }                                                                           \
    VMCNT0;                                                                     \
    BARRIER;

// ============ QKV GEMM ============
__global__ __launch_bounds__(512, 4) void k_gemm_qkv256(const h16* __restrict__ Xh,
                                                        const h16* __restrict__ Wt,
                                                        h16* __restrict__ qk,
                                                        h16* __restrict__ vt) {
    extern __shared__ char smem[];
    const int t = threadIdx.x;
    const int lane = t & 63, wave = t >> 6;
    const int wr = wave >> 2, wc = wave & 3;
    const int fr = lane & 15, kq = lane >> 4;
    const int sw = fr & 3;
    const int loff = (((t & 3) ^ ((t >> 2) & 3)) * 8);
    const size_t ldab = 1024;

    int bid = blockIdx.x;
    bid = (bid & 7) * 96 + (bid >> 3);        // XCD swizzle (768 % 8 == 0)
    const int nt = bid % 12, mt = bid / 12;
    const int rowBase = mt * 256;
    const int colBaseF = nt * 256;
    const int which = nt >> 2;
    const int nc0 = colBaseF & 1023;
    const h16* A  = Xh;
    const h16* Bt = Wt + (size_t)which * (1024 * 1024);

    f32x4 acc[2][2][4][2];
#pragma unroll
    for (int mh = 0; mh < 2; ++mh)
#pragma unroll
        for (int nh = 0; nh < 2; ++nh)
#pragma unroll
            for (int q = 0; q < 4; ++q)
#pragma unroll
                for (int nf = 0; nf < 2; ++nf)
                    acc[mh][nh][q][nf] = (f32x4){0.f, 0.f, 0.f, 0.f};
    f16x8 a[4], b[2];

    CORE_LOOP(32)

    const int bat  = rowBase >> 11;
    const int tloc = rowBase & 2047;

    if (which < 2) {
        h16* dst = qk + (size_t)bat * 4194304 + (which == 1 ? 2097152u : 0u);
#pragma unroll
        for (int mh = 0; mh < 2; ++mh)
#pragma unroll
            for (int nh = 0; nh < 2; ++nh)
#pragma unroll
                for (int q = 0; q < 4; ++q)
#pragma unroll
                    for (int nf = 0; nf < 2; ++nf) {
                        int cc = nc0 + nh * 128 + wc * 32 + nf * 16 + fr;
#pragma unroll
                        for (int j = 0; j < 4; ++j) {
                            int rr = tloc + mh * 128 + wr * 64 + q * 16 + kq * 4 + j;
                            dst[(size_t)rr * 1024 + cc] = (h16)acc[mh][nh][q][nf][j];
                        }
                    }
    } else {
        // V-transpose through LDS, 4 half-passes (fits 64 KiB): LT[128][136]
        h16* LT = (h16*)smem;
        const size_t bvt = (size_t)bat * 2097152;
#pragma unroll
        for (int mh = 0; mh < 2; ++mh)
#pragma unroll
            for (int nh = 0; nh < 2; ++nh) {
                __syncthreads();
#pragma unroll
                for (int q = 0; q < 4; ++q)
#pragma unroll
                    for (int nf = 0; nf < 2; ++nf) {
                        int cl = wc * 32 + nf * 16 + fr;     // 0..127 within half
#pragma unroll
                        for (int j = 0; j < 4; ++j) {
                            int rl = wr * 64 + q * 16 + kq * 4 + j;
                            LT[cl * 136 + rl] = (h16)acc[mh][nh][q][nf][j];
                        }
                    }
                __syncthreads();
#pragma unroll
                for (int p = 0; p < 4; ++p) {
                    int idx = t + p * 512;
                    int nl = idx >> 4;                        // 0..127
                    int tc = (idx & 15) * 8;
                    *(f16x8*)&vt[bvt + (size_t)(nc0 + nh * 128 + nl) * 2048
                                 + tloc + mh * 128 + tc] =
                        *(f16x8*)&LT[nl * 136 + tc];
                }
            }
    }
}

// ============ S_all: S16 = s - segmax epilogue (BIG path) ==========
__global__ __launch_bounds__(512, 4) void k_sgemm256(const h16* __restrict__ qkin,
                                                     h16* __restrict__ s16,
                                                     float* __restrict__ smax) {
    extern __shared__ char smem[];
    const int t = threadIdx.x;
    const int lane = t & 63, wave = t >> 6;
    const int wr = wave >> 2, wc = wave & 3;
    const int fr = lane & 15, kq = lane >> 4;
    const int sw = fr & 3;
    const int loff = (((t & 3) ^ ((t >> 2) & 3)) * 8);
    const size_t ldab = 1024;

    int bid = blockIdx.x;
    bid = (bid & 7) * 64 + (bid >> 3);        // XCD swizzle (512 % 8 == 0)
    const int sb = bid >> 6;
    const int tile = bid & 63;
    const int rowBase = (tile >> 3) * 256;
    const int nc0 = (tile & 7) * 256;
    const h16* A  = qkin + (size_t)sb * 4194304;   // Q_b
    const h16* Bt = A + 2097152;                   // K_b

    f32x4 acc[2][2][4][2];
#pragma unroll
    for (int mh = 0; mh < 2; ++mh)
#pragma unroll
        for (int nh = 0; nh < 2; ++nh)
#pragma unroll
            for (int q = 0; q < 4; ++q)
#pragma unroll
                for (int nf = 0; nf < 2; ++nf)
                    acc[mh][nh][q][nf] = (f32x4){0.f, 0.f, 0.f, 0.f};
    f16x8 a[4], b[2];

    CORE_LOOP(32)

    h16*   srow = s16 + (size_t)sb * 4194304;
    float* smx  = smax + (size_t)sb * 131072;
#pragma unroll
    for (int mh = 0; mh < 2; ++mh)
#pragma unroll
        for (int nh = 0; nh < 2; ++nh) {
            const int segIdx = (nc0 >> 5) + nh * 4 + wc;
#pragma unroll
            for (int q = 0; q < 4; ++q)
#pragma unroll
                for (int j = 0; j < 4; ++j) {
                    float mx = fmaxf(acc[mh][nh][q][0][j], acc[mh][nh][q][1][j]);
                    mx = fmaxf(mx, __shfl_xor(mx, 1));
                    mx = fmaxf(mx, __shfl_xor(mx, 2));
                    mx = fmaxf(mx, __shfl_xor(mx, 4));
                    mx = fmaxf(mx, __shfl_xor(mx, 8));
                    int rr = rowBase + mh * 128 + wr * 64 + q * 16 + kq * 4 + j;
#pragma unroll
                    for (int nf = 0; nf < 2; ++nf) {
                        int cc = nc0 + nh * 128 + wc * 32 + nf * 16 + fr;
                        srow[(size_t)rr * 2048 + cc] = (h16)(acc[mh][nh][q][nf][j] - mx);
                    }
                    if (fr == 0) smx[rr * 64 + segIdx] = mx;
                }
        }
}

// ============ O_all: K=2048, P(fp16 in S16) @ Vt^T (BIG path) ======
__global__ __launch_bounds__(512, 4) void k_ogemm256(const h16* __restrict__ p16,
                                                     const h16* __restrict__ vt,
                                                     float* __restrict__ Oall) {
    extern __shared__ char smem[];
    const int t = threadIdx.x;
    const int lane = t & 63, wave = t >> 6;
    const int wr = wave >> 2, wc = wave & 3;
    const int fr = lane & 15, kq = lane >> 4;
    const int sw = fr & 3;
    const int loff = (((t & 3) ^ ((t >> 2) & 3)) * 8);
    const size_t ldab = 2048;

    int bid = blockIdx.x;
    bid = (bid & 7) * 32 + (bid >> 3);        // XCD swizzle (256 % 8 == 0)
    const int sb = bid >> 5;
    const int tile = bid & 31;
    const int rowBase = (tile >> 2) * 256;
    const int nc0 = (tile & 3) * 256;
    const h16* A  = p16 + (size_t)sb * 4194304;   // P_b  [2048 x 2048]
    const h16* Bt = vt + (size_t)sb * 2097152;    // Vt_b [1024 x 2048]

    f32x4 acc[2][2][4][2];
#pragma unroll
    for (int mh = 0; mh < 2; ++mh)
#pragma unroll
        for (int nh = 0; nh < 2; ++nh)
#pragma unroll
            for (int q = 0; q < 4; ++q)
#pragma unroll
                for (int nf = 0; nf < 2; ++nf)
                    acc[mh][nh][q][nf] = (f32x4){0.f, 0.f, 0.f, 0.f};
    f16x8 a[4], b[2];

    CORE_LOOP(64)

    float* Ob = Oall + (size_t)sb * 2097152;
#pragma unroll
    for (int mh = 0; mh < 2; ++mh)
#pragma unroll
        for (int nh = 0; nh < 2; ++nh)
#pragma unroll
            for (int q = 0; q < 4; ++q)
#pragma unroll
                for (int nf = 0; nf < 2; ++nf) {
                    int cc = nc0 + nh * 128 + wc * 32 + nf * 16 + fr;
#pragma unroll
                    for (int j = 0; j < 4; ++j) {
                        int rr = rowBase + mh * 128 + wr * 64 + q * 16 + kq * 4 + j;
                        Ob[(size_t)rr * 1024 + cc] = acc[mh][nh][q][nf][j];
                    }
                }
}

// ============ SM_all: softmax over s16 (+segmax), in place (BIG path) =====
__global__ __launch_bounds__(256) void k_softmax16(h16* __restrict__ s16,
                                                   const float* __restrict__ smax) {
    int row = blockIdx.x, t = threadIdx.x;
    const float* smx = smax + (size_t)row * 64;
    float m = smx[t & 63];
#pragma unroll
    for (int off = 32; off; off >>= 1) m = fmaxf(m, __shfl_xor(m, off));

    h16* sr = s16 + (size_t)row * 2048 + t * 8;
    f16x8 v = *(f16x8*)sr;
    float msg = smx[t >> 2] - m;
    float e[8];
#pragma unroll
    for (int i = 0; i < 8; ++i) e[i] = __expf((float)v[i] + msg);
    float s = ((e[0] + e[1]) + (e[2] + e[3])) + ((e[4] + e[5]) + (e[6] + e[7]));
#pragma unroll
    for (int off = 32; off; off >>= 1) s += __shfl_xor(s, off);
    __shared__ float reds[4];
    if ((t & 63) == 0) reds[t >> 6] = s;
    __syncthreads();
    s = (reds[0] + reds[1]) + (reds[2] + reds[3]);
    float inv = 1.0f / s;
    f16x8 o;
#pragma unroll
    for (int i = 0; i < 8; ++i) o[i] = (h16)(e[i] * inv);
    *(f16x8*)sr = o;
}

// ============ paired attention GEMM (r8 core; SMALL path only) ========
__global__ __launch_bounds__(256) void k_attn_pair(const h16* __restrict__ QKg,
                                                   float* __restrict__ Sbuf,
                                                   const h16* __restrict__ Pbuf,
                                                   const h16* __restrict__ Vtg,
                                                   float* __restrict__ Og,
                                                   int nS) {
    extern __shared__ char smem[];
    int bid = blockIdx.x;
    const int cpx = gridDim.x >> 3;
    bid = (bid & 7) * cpx + (bid >> 3);

    const int t = threadIdx.x;
    const int lane = t & 63, wave = t >> 6;
    const int wr = wave >> 1, wc = wave & 1;
    const int fr = lane & 15, kq = lane >> 4, fj = (lane >> 4) * 4;
    const int sw8 = fr & 7;
    const int loff8 = (((t & 7) ^ ((t >> 3) & 7)) * 8);

    const h16 *A, *Bt;
    float* C;
    int K, lda, ldb, ldc, rowBase, colBase;
    if (bid < nS) {
        int sb = bid >> 8, tile = bid & 255;
        rowBase = (tile >> 4) * 128; colBase = (tile & 15) * 128;
        A   = QKg + (size_t)sb * 4194304;
        Bt  = A + 2097152;
        C   = Sbuf + (size_t)sb * 4194304;
        K = 1024; lda = 1024; ldb = 1024; ldc = 2048;
    } else {
        int ob = bid - nS;
        int sb = ob >> 7, tile = ob & 127;
        rowBase = (tile >> 3) * 128; colBase = (tile & 7) * 128;
        A   = Pbuf + (size_t)sb * 4194304;
        Bt  = Vtg + (size_t)sb * 2097152;
        C   = Og + (size_t)sb * 2097152;
        K = 2048; lda = 2048; ldb = 2048; ldc = 1024;
    }

    const h16* Asrc = A + (size_t)(rowBase + (t >> 3)) * lda + loff8;
    const h16* Bsrc = Bt + (size_t)(colBase + (t >> 3)) * ldb + loff8;
    const size_t a32 = (size_t)32 * lda, b32 = (size_t)32 * ldb;

#define STG2(BUF, KT) do {                                                    \
        char* _ba = smem + (BUF) * 32768 + t * 16;                            \
        char* _bb = _ba + 16384;                                              \
        GLD16(Asrc + (KT), _ba);                                              \
        GLD16(Asrc + (KT) + a32, _ba + 4096);                                 \
        GLD16(Asrc + (KT) + 2 * a32, _ba + 8192);                             \
        GLD16(Asrc + (KT) + 3 * a32, _ba + 12288);                            \
        GLD16(Bsrc + (KT), _bb);                                              \
        GLD16(Bsrc + (KT) + b32, _bb + 4096);                                 \
        GLD16(Bsrc + (KT) + 2 * b32, _bb + 8192);                             \
        GLD16(Bsrc + (KT) + 3 * b32, _bb + 12288);                            \
    } while (0)

    f32x4 acc[4][4];
#pragma unroll
    for (int m = 0; m < 4; ++m)
#pragma unroll
        for (int n = 0; n < 4; ++n) acc[m][n] = (f32x4){0.f, 0.f, 0.f, 0.f};

#define RDF(BASE, R, S) \
    (*(const f16x8*)(smem + (BASE) + (R) * 128 + (((S) ^ sw8) << 4)))

#define MFMA_BUF(BUF) do {                                                    \
        f16x8 af[4][2], bf[4][2];                                             \
        _Pragma("unroll") for (int m = 0; m < 4; ++m)                         \
        _Pragma("unroll") for (int ks = 0; ks < 2; ++ks)                      \
            af[m][ks] = RDF((BUF) * 32768,                                    \
                            wr * 64 + m * 16 + fr, kq + ks * 4);              \
        _Pragma("unroll") for (int n = 0; n < 4; ++n)                         \
        _Pragma("unroll") for (int ks = 0; ks < 2; ++ks)                      \
            bf[n][ks] = RDF((BUF) * 32768 + 16384,                            \
                            wc * 64 + n * 16 + fr, kq + ks * 4);              \
        _Pragma("unroll") for (int m = 0; m < 4; ++m)                         \
        _Pragma("unroll") for (int n = 0; n < 4; ++n)                         \
        _Pragma("unroll") for (int ks = 0; ks < 2; ++ks)                      \
            acc[m][n] = __builtin_amdgcn_mfma_f32_16x16x32_f16(               \
                af[m][ks], bf[n][ks], acc[m][n], 0, 0, 0);                    \
    } while (0)

    STG2(0, 0);
    __syncthreads();
    int cur = 0;
    for (int kt = 64; kt < K; kt += 64) {
        STG2(cur ^ 1, kt);
        MFMA_BUF(cur);
        __syncthreads();
        cur ^= 1;
    }
    MFMA_BUF(cur);

#pragma unroll
    for (int m = 0; m < 4; ++m)
#pragma unroll
        for (int n = 0; n < 4; ++n) {
            int cc = colBase + wc * 64 + n * 16 + fr;
#pragma unroll
            for (int j = 0; j < 4; ++j) {
                int rr = rowBase + wr * 64 + m * 16 + fj + j;
                C[(size_t)rr * ldc + cc] = acc[m][n][j];
            }
        }
#undef STG2
#undef RDF
#undef MFMA_BUF
}

// ---------------- fallback softmax: S fp32 -> P fp16 ----------------
__global__ __launch_bounds__(256) void k_softmax(const float* __restrict__ S,
                                                 h16* __restrict__ P) {
    int row = blockIdx.x, t = threadIdx.x;
    const float* sr = S + (size_t)row * 2048 + t * 8;
    f32x4 a = *(const f32x4*)sr;
    f32x4 b = *(const f32x4*)(sr + 4);
    float m = fmaxf(fmaxf(fmaxf(a[0], a[1]), fmaxf(a[2], a[3])),
                    fmaxf(fmaxf(b[0], b[1]), fmaxf(b[2], b[3])));
#pragma unroll
    for (int off = 32; off; off >>= 1) m = fmaxf(m, __shfl_xor(m, off));
    __shared__ float redm[4], reds[4];
    if ((t & 63) == 0) redm[t >> 6] = m;
    __syncthreads();
    m = fmaxf(fmaxf(redm[0], redm[1]), fmaxf(redm[2], redm[3]));

    float e[8];
    e[0] = __expf(a[0] - m); e[1] = __expf(a[1] - m);
    e[2] = __expf(a[2] - m); e[3] = __expf(a[3] - m);
    e[4] = __expf(b[0] - m); e[5] = __expf(b[1] - m);
    e[6] = __expf(b[2] - m); e[7] = __expf(b[3] - m);
    float s = ((e[0] + e[1]) + (e[2] + e[3])) + ((e[4] + e[5]) + (e[6] + e[7]));
#pragma unroll
    for (int off = 32; off; off >>= 1) s += __shfl_xor(s, off);
    if ((t & 63) == 0) reds[t >> 6] = s;
    __syncthreads();
    s = (reds[0] + reds[1]) + (reds[2] + reds[3]);
    float inv = 1.0f / s;
    f16x8 o;
#pragma unroll
    for (int i = 0; i < 8; ++i) o[i] = (h16)(e[i] * inv);
    *(f16x8*)(P + (size_t)row * 2048 + t * 8) = o;
}

extern "C" void kernel_launch(void* const* d_in, const int* in_sizes, int n_in,
                              void* d_out, int out_size, void* d_ws, size_t ws_size,
                              hipStream_t stream) {
    (void)in_sizes; (void)n_in; (void)out_size;
    const float* X  = (const float*)d_in[0];
    const float* Wq = (const float*)d_in[1];
    const float* Wk = (const float*)d_in[2];
    const float* Wv = (const float*)d_in[3];

    char* ws = (char*)d_ws;
    h16*   Xh = (h16*)ws;
    h16*   Wt = (h16*)(ws + 33554432);
    h16*   Vt = (h16*)(ws + 39845888);
    h16*   QK = (h16*)d_out;
    float* O  = (float*)d_out;

    hipFuncSetAttribute((const void*)k_gemm_qkv256,
                        hipFuncAttributeMaxDynamicSharedMemorySize, 65536);
    hipFuncSetAttribute((const void*)k_sgemm256,
                        hipFuncAttributeMaxDynamicSharedMemorySize, 65536);
    hipFuncSetAttribute((const void*)k_ogemm256,
                        hipFuncAttributeMaxDynamicSharedMemorySize, 65536);
    hipFuncSetAttribute((const void*)k_attn_pair,
                        hipFuncAttributeMaxDynamicSharedMemorySize, 65536);

    k_conv<<<8960, 256, 0, stream>>>(X, Xh, Wq, Wk, Wv, Wt);
    k_gemm_qkv256<<<768, 512, 65536, stream>>>(Xh, Wt, QK, Vt);

    if (ws_size >= 144703488u) {
        // ---- BIG path: flat chain, fp16 seg-max S ----
        h16*   S16  = (h16*)(ws + 73400320);
        float* Smax = (float*)(ws + 140509184);
        k_sgemm256<<<512, 512, 65536, stream>>>(QK, S16, Smax);
        k_softmax16<<<16384, 256, 0, stream>>>(S16, Smax);
        k_ogemm256<<<256, 512, 65536, stream>>>(S16, Vt, O);
    } else {
        // ---- SMALL path: r10 chain ----
        float* S = (float*)ws;
        h16*   P = (h16*)(ws + 73400320);
        const size_t QKstride = 2 * 4194304;
        const size_t Vstride  = 2 * 2097152;
        k_attn_pair<<<512, 256, 65536, stream>>>(QK, S, P, Vt, O, 512);
        k_softmax<<<4096, 256, 0, stream>>>(S, P);
        for (int g = 1; g < 4; ++g) {
            k_attn_pair<<<768, 256, 65536, stream>>>(
                QK + (size_t)g * QKstride, S,
                P, Vt + (size_t)(g - 1) * Vstride, O + (size_t)(g - 1) * Vstride, 512);
            k_softmax<<<4096, 256, 0, stream>>>(S, P);
        }
        k_attn_pair<<<256, 256, 65536, stream>>>(
            QK, S, P, Vt + 3 * Vstride, O + 3 * Vstride, 0);
    }
}

// Round 14
// 295.376 us; speedup vs baseline: 8.4188x; 8.4188x over previous
//
#include <hip/hip_runtime.h>
#include <stdint.h>

typedef _Float16 h16;
typedef __attribute__((ext_vector_type(8))) _Float16 f16x8;
typedef __attribute__((ext_vector_type(4))) float f32x4;

// Problem: B=8, T=2048, D=1024, NODES=1024  (fp32 in/out)
//
// Shared ws prefix (both paths):
//   Xh  @ 0         : 33554432   (X fp16)            -- dead after qkv
//   Wt  @ 33554432  : 6291456    (W^T fp16 [n][d])   -- dead after qkv
//   Vt  @ 39845888  : 33554432   (V^T fp16 [b][n][t])-- live to end
// BIG path (ws >= 144703488): flat chain, S stored fp16 relative to seg-max:
//   S16 @ 73400320  : 67108864   ([b][row][2048] h16 = s - m_seg; P in-place)
//   Smax@ 140509184 : 4194304    ([b][row][64] f32 per-32col-seg max)
//   chain: conv, qkv256, S_all(512), SM_all(16384), O_all(256, 8-phase)
// GEMM core: 256x256 8-phase, BK=64, 128 KiB LDS (r12 proven core).
// SMALL path (r10 fallback): group-of-2 pairing chain.
// Q,K fp16 live in d_out per-batch [Q_b|K_b] 8 MiB; O_b fp32 overwrites it.

#define GLD16(gsrc, ldst)                                                     \
    __builtin_amdgcn_global_load_lds(                                         \
        (const __attribute__((address_space(1))) uint32_t*)(gsrc),            \
        (__attribute__((address_space(3))) uint32_t*)(ldst), 16, 0, 0)

#define FENCE asm volatile("" ::: "memory")
#define BARRIER do { FENCE; __builtin_amdgcn_s_barrier(); FENCE; } while (0)
#define LGKM0  asm volatile("s_waitcnt lgkmcnt(0)" ::: "memory")
#define VMCNT4 asm volatile("s_waitcnt vmcnt(4)" ::: "memory")
#define VMCNT0 asm volatile("s_waitcnt vmcnt(0)" ::: "memory")

// ---------------- merged conversion kernel ----------------
__global__ __launch_bounds__(256) void k_conv(const float* __restrict__ X,
                                              h16* __restrict__ Xh,
                                              const float* __restrict__ W0,
                                              const float* __restrict__ W1,
                                              const float* __restrict__ W2,
                                              h16* __restrict__ Wt) {
    __shared__ h16 LT[64 * 72];
    int t = threadIdx.x;
    if (blockIdx.x < 8192) {
        size_t i = ((size_t)blockIdx.x * 256 + t) * 8;
        f32x4 a = *(const f32x4*)(X + i);
        f32x4 b = *(const f32x4*)(X + i + 4);
        f16x8 o;
        o[0] = (h16)a[0]; o[1] = (h16)a[1]; o[2] = (h16)a[2]; o[3] = (h16)a[3];
        o[4] = (h16)b[0]; o[5] = (h16)b[1]; o[6] = (h16)b[2]; o[7] = (h16)b[3];
        *(f16x8*)(Xh + i) = o;
        return;
    }
    int bid2 = blockIdx.x - 8192;
    int which = bid2 >> 8;
    int tile  = bid2 & 255;
    int d0 = (tile >> 4) * 64, n0 = (tile & 15) * 64;
    const float* W = (which == 0) ? W0 : ((which == 1) ? W1 : W2);
    h16* dst = Wt + (size_t)which * (1024 * 1024);
#pragma unroll
    for (int p = 0; p < 4; ++p) {
        int c = t + p * 256;
        int r = c >> 4;
        int cf = (c & 15) * 4;
        f32x4 v = *(const f32x4*)&W[(size_t)(d0 + r) * 1024 + n0 + cf];
#pragma unroll
        for (int e = 0; e < 4; ++e) LT[(cf + e) * 72 + r] = (h16)v[e];
    }
    __syncthreads();
#pragma unroll
    for (int p = 0; p < 2; ++p) {
        int q = t + p * 256;
        int nl = q >> 3;
        int dc = (q & 7) * 8;
        f16x8 v = *(f16x8*)&LT[nl * 72 + dc];
        *(f16x8*)&dst[(size_t)(n0 + nl) * 1024 + d0 + dc] = v;
    }
}

// ===== shared 256x256 8-phase core macros (BK=64, 128 KiB LDS; r12 proven) =====
// Require locals: smem, t, loff, sw, A, Bt, rowBase, nc0, wr, wc, fr, kq,
//                 acc, a, b, and compile-time-const size_t ldab (row stride).
#define STAGE_OP(OPREG, OPPTR, OPROW, BUF, H, KT) do {                          \
        const h16* _src = (OPPTR) + (size_t)((OPROW) + (H) * 128 + (t >> 3)) * ldab \
                          + (KT) * 64 + loff;                                   \
        char* _dst = smem + (OPREG) + (BUF) * 32768 + (H) * 16384 + t * 16;     \
        GLD16(_src, _dst);                                                      \
        GLD16(_src + 64 * ldab, _dst + 8192);                                   \
    } while (0)
#define STAGE_A(BUF, H, KT) STAGE_OP(0, A, rowBase, BUF, H, KT)
#define STAGE_B(BUF, H, KT) STAGE_OP(65536, Bt, nc0, BUF, H, KT)

#define RD(REG, ROW, SLOT) \
    (*(const f16x8*)(smem + (REG) + (ROW) * 128 + ((((SLOT)) ^ sw) << 4)))

#define PH(BUF, MH, NH, DOA, STG, VM) do {                                      \
        if (DOA) {                                                              \
            _Pragma("unroll") for (int q = 0; q < 4; ++q)                       \
            _Pragma("unroll") for (int ks = 0; ks < 2; ++ks)                    \
                a[q][ks] = RD((BUF) * 32768,                                    \
                              (MH) * 128 + wr * 64 + q * 16 + fr, kq + ks * 4); \
        }                                                                       \
        _Pragma("unroll") for (int nf = 0; nf < 2; ++nf)                        \
        _Pragma("unroll") for (int ks = 0; ks < 2; ++ks)                        \
            b[nf][ks] = RD(65536 + (BUF) * 32768,                               \
                           (NH) * 128 + wc * 32 + nf * 16 + fr, kq + ks * 4);   \
        STG;                                                                    \
        VM;                                                                     \
        BARRIER; LGKM0;                                                         \
        __builtin_amdgcn_s_setprio(1);                                          \
        _Pragma("unroll") for (int q = 0; q < 4; ++q)                           \
        _Pragma("unroll") for (int nf = 0; nf < 2; ++nf)                        \
        _Pragma("unroll") for (int ks = 0; ks < 2; ++ks)                        \
            acc[MH][NH][q][nf] = __builtin_amdgcn_mfma_f32_16x16x32_f16(        \
                a[q][ks], b[nf][ks], acc[MH][NH][q][nf], 0, 0, 0);              \
        __builtin_amdgcn_s_setprio(0);                                          \
        BARRIER;                                                                \
    } while (0)

// NTT = number of 64-wide K-tiles (power of 2). Wrap staging via &(NTT-1).
#define CORE_LOOP(NTT)                                                          \
    STAGE_A(0, 0, 0); STAGE_A(0, 1, 0);                                         \
    STAGE_B(0, 0, 0); STAGE_B(0, 1, 0);                                         \
    STAGE_A(1, 0, 1); STAGE_B(1, 0, 1);                                         \
    VMCNT4;                                                                     \
    BARRIER;                                                                    \
    for (int i = 0; i < (NTT) / 2; ++i) {                                       \
        const int tb  = 2 * i + 1;                                              \
        const int tc2 = (2 * i + 2) & ((NTT) - 1);                              \
        const int td  = (2 * i + 3) & ((NTT) - 1);                              \
        PH(0, 0, 0, 1, STAGE_A(1, 1, tb),  (void)0);                            \
        PH(0, 0, 1, 0, STAGE_B(1, 1, tb),  (void)0);                            \
        PH(0, 1, 0, 1, STAGE_A(0, 0, tc2), (void)0);                            \
        PH(0, 1, 1, 0, STAGE_B(0, 0, tc2), VMCNT4);                             \
        PH(1, 0, 0, 1, STAGE_A(0, 1, tc2), (void)0);                            \
        PH(1, 0, 1, 0, STAGE_B(0, 1, tc2), (void)0);                            \
        PH(1, 1, 0, 1, STAGE_A(1, 0, td),  (void)0);                            \
        PH(1, 1, 1, 0, STAGE_B(1, 0, td),  VMCNT4);                             \
    }                                                                           \
    VMCNT0;                                                                     \
    BARRIER;

// ============ 256x256 8-phase QKV GEMM ============
__global__ __launch_bounds__(512, 2) void k_gemm_qkv256(const h16* __restrict__ Xh,
                                                        const h16* __restrict__ Wt,
                                                        h16* __restrict__ qk,
                                                        h16* __restrict__ vt) {
    extern __shared__ char smem[];
    const int t = threadIdx.x;
    const int lane = t & 63, wave = t >> 6;
    const int wr = wave >> 2, wc = wave & 3;
    const int fr = lane & 15, kq = lane >> 4;
    const int sw = fr & 7;
    const int loff = (((t & 7) ^ ((t >> 3) & 7)) * 8);
    const size_t ldab = 1024;

    int bid = blockIdx.x;
    bid = (bid & 7) * 96 + (bid >> 3);        // XCD swizzle (768 % 8 == 0)
    const int nt = bid % 12, mt = bid / 12;
    const int rowBase = mt * 256;
    const int colBaseF = nt * 256;
    const int which = nt >> 2;
    const int nc0 = colBaseF & 1023;
    const h16* A  = Xh;
    const h16* Bt = Wt + (size_t)which * (1024 * 1024);

    f32x4 acc[2][2][4][2];
#pragma unroll
    for (int mh = 0; mh < 2; ++mh)
#pragma unroll
        for (int nh = 0; nh < 2; ++nh)
#pragma unroll
            for (int q = 0; q < 4; ++q)
#pragma unroll
                for (int nf = 0; nf < 2; ++nf)
                    acc[mh][nh][q][nf] = (f32x4){0.f, 0.f, 0.f, 0.f};
    f16x8 a[4][2], b[2][2];

    CORE_LOOP(16)

    const int bat  = rowBase >> 11;
    const int tloc = rowBase & 2047;

    if (which < 2) {
        h16* dst = qk + (size_t)bat * 4194304 + (which == 1 ? 2097152u : 0u);
#pragma unroll
        for (int mh = 0; mh < 2; ++mh)
#pragma unroll
            for (int nh = 0; nh < 2; ++nh)
#pragma unroll
                for (int q = 0; q < 4; ++q)
#pragma unroll
                    for (int nf = 0; nf < 2; ++nf) {
                        int cc = nc0 + nh * 128 + wc * 32 + nf * 16 + fr;
#pragma unroll
                        for (int j = 0; j < 4; ++j) {
                            int rr = tloc + mh * 128 + wr * 64 + q * 16 + kq * 4 + j;
                            dst[(size_t)rr * 1024 + cc] = (h16)acc[mh][nh][q][nf][j];
                        }
                    }
    } else {
        h16* LT = (h16*)smem;  // [256 n][136 t-pad]
        const size_t bvt = (size_t)bat * 2097152;
#pragma unroll
        for (int mh = 0; mh < 2; ++mh) {
            __syncthreads();
#pragma unroll
            for (int nh = 0; nh < 2; ++nh)
#pragma unroll
                for (int q = 0; q < 4; ++q)
#pragma unroll
                    for (int nf = 0; nf < 2; ++nf) {
                        int cl = nh * 128 + wc * 32 + nf * 16 + fr;
#pragma unroll
                        for (int j = 0; j < 4; ++j) {
                            int rl = wr * 64 + q * 16 + kq * 4 + j;
                            LT[cl * 136 + rl] = (h16)acc[mh][nh][q][nf][j];
                        }
                    }
            __syncthreads();
#pragma unroll
            for (int p = 0; p < 8; ++p) {
                int idx = t + p * 512;
                int nl = idx >> 4;
                int tc = (idx & 15) * 8;
                *(f16x8*)&vt[bvt + (size_t)(nc0 + nl) * 2048 + tloc + mh * 128 + tc] =
                    *(f16x8*)&LT[nl * 136 + tc];
            }
        }
    }
}

// ============ S_all: 256x256 8-phase, S16 = s - segmax epilogue (BIG path) ==========
__global__ __launch_bounds__(512, 2) void k_sgemm256(const h16* __restrict__ qkin,
                                                     h16* __restrict__ s16,
                                                     float* __restrict__ smax) {
    extern __shared__ char smem[];
    const int t = threadIdx.x;
    const int lane = t & 63, wave = t >> 6;
    const int wr = wave >> 2, wc = wave & 3;
    const int fr = lane & 15, kq = lane >> 4;
    const int sw = fr & 7;
    const int loff = (((t & 7) ^ ((t >> 3) & 7)) * 8);
    const size_t ldab = 1024;

    int bid = blockIdx.x;
    bid = (bid & 7) * 64 + (bid >> 3);        // XCD swizzle (512 % 8 == 0)
    const int sb = bid >> 6;
    const int tile = bid & 63;
    const int rowBase = (tile >> 3) * 256;
    const int nc0 = (tile & 7) * 256;
    const h16* A  = qkin + (size_t)sb * 4194304;   // Q_b  [2048 x 1024]
    const h16* Bt = A + 2097152;                   // K_b  [2048 x 1024]

    f32x4 acc[2][2][4][2];
#pragma unroll
    for (int mh = 0; mh < 2; ++mh)
#pragma unroll
        for (int nh = 0; nh < 2; ++nh)
#pragma unroll
            for (int q = 0; q < 4; ++q)
#pragma unroll
                for (int nf = 0; nf < 2; ++nf)
                    acc[mh][nh][q][nf] = (f32x4){0.f, 0.f, 0.f, 0.f};
    f16x8 a[4][2], b[2][2];

    CORE_LOOP(16)

    h16*   srow = s16 + (size_t)sb * 4194304;      // [2048][2048] h16
    float* smx  = smax + (size_t)sb * 131072;      // [2048][64]   f32
#pragma unroll
    for (int mh = 0; mh < 2; ++mh)
#pragma unroll
        for (int nh = 0; nh < 2; ++nh) {
            const int segIdx = (nc0 >> 5) + nh * 4 + wc;
#pragma unroll
            for (int q = 0; q < 4; ++q)
#pragma unroll
                for (int j = 0; j < 4; ++j) {
                    float mx = fmaxf(acc[mh][nh][q][0][j], acc[mh][nh][q][1][j]);
                    mx = fmaxf(mx, __shfl_xor(mx, 1));
                    mx = fmaxf(mx, __shfl_xor(mx, 2));
                    mx = fmaxf(mx, __shfl_xor(mx, 4));
                    mx = fmaxf(mx, __shfl_xor(mx, 8));
                    int rr = rowBase + mh * 128 + wr * 64 + q * 16 + kq * 4 + j;
#pragma unroll
                    for (int nf = 0; nf < 2; ++nf) {
                        int cc = nc0 + nh * 128 + wc * 32 + nf * 16 + fr;
                        srow[(size_t)rr * 2048 + cc] = (h16)(acc[mh][nh][q][nf][j] - mx);
                    }
                    if (fr == 0) smx[rr * 64 + segIdx] = mx;
                }
        }
}

// ============ O_all: 256x256 8-phase, K=2048, P(fp16 in S16) @ Vt^T (BIG path) ======
// grid 256 = 8 batches x (8 mt x 4 nt) -> exactly 1 block/CU, single pass.
__global__ __launch_bounds__(512, 2) void k_ogemm256(const h16* __restrict__ p16,
                                                     const h16* __restrict__ vt,
                                                     float* __restrict__ Oall) {
    extern __shared__ char smem[];
    const int t = threadIdx.x;
    const int lane = t & 63, wave = t >> 6;
    const int wr = wave >> 2, wc = wave & 3;
    const int fr = lane & 15, kq = lane >> 4;
    const int sw = fr & 7;
    const int loff = (((t & 7) ^ ((t >> 3) & 7)) * 8);
    const size_t ldab = 2048;

    int bid = blockIdx.x;
    bid = (bid & 7) * 32 + (bid >> 3);        // XCD swizzle (256 % 8 == 0)
    const int sb = bid >> 5;                  // batch
    const int tile = bid & 31;                // 8 mt x 4 nt
    const int rowBase = (tile >> 2) * 256;
    const int nc0 = (tile & 3) * 256;
    const h16* A  = p16 + (size_t)sb * 4194304;   // P_b  [2048 x 2048]
    const h16* Bt = vt + (size_t)sb * 2097152;    // Vt_b [1024 x 2048]

    f32x4 acc[2][2][4][2];
#pragma unroll
    for (int mh = 0; mh < 2; ++mh)
#pragma unroll
        for (int nh = 0; nh < 2; ++nh)
#pragma unroll
            for (int q = 0; q < 4; ++q)
#pragma unroll
                for (int nf = 0; nf < 2; ++nf)
                    acc[mh][nh][q][nf] = (f32x4){0.f, 0.f, 0.f, 0.f};
    f16x8 a[4][2], b[2][2];

    CORE_LOOP(32)

    float* Ob = Oall + (size_t)sb * 2097152;
#pragma unroll
    for (int mh = 0; mh < 2; ++mh)
#pragma unroll
        for (int nh = 0; nh < 2; ++nh)
#pragma unroll
            for (int q = 0; q < 4; ++q)
#pragma unroll
                for (int nf = 0; nf < 2; ++nf) {
                    int cc = nc0 + nh * 128 + wc * 32 + nf * 16 + fr;
#pragma unroll
                    for (int j = 0; j < 4; ++j) {
                        int rr = rowBase + mh * 128 + wr * 64 + q * 16 + kq * 4 + j;
                        Ob[(size_t)rr * 1024 + cc] = acc[mh][nh][q][nf][j];
                    }
                }
}

// ============ SM_all: softmax over s16 (+segmax), P written in place (BIG path) =====
__global__ __launch_bounds__(256) void k_softmax16(h16* __restrict__ s16,
                                                   const float* __restrict__ smax) {
    int row = blockIdx.x, t = threadIdx.x;
    const float* smx = smax + (size_t)row * 64;
    float m = smx[t & 63];
#pragma unroll
    for (int off = 32; off; off >>= 1) m = fmaxf(m, __shfl_xor(m, off));

    h16* sr = s16 + (size_t)row * 2048 + t * 8;
    f16x8 v = *(f16x8*)sr;
    float msg = smx[t >> 2] - m;
    float e[8];
#pragma unroll
    for (int i = 0; i < 8; ++i) e[i] = __expf((float)v[i] + msg);
    float s = ((e[0] + e[1]) + (e[2] + e[3])) + ((e[4] + e[5]) + (e[6] + e[7]));
#pragma unroll
    for (int off = 32; off; off >>= 1) s += __shfl_xor(s, off);
    __shared__ float reds[4];
    if ((t & 63) == 0) reds[t >> 6] = s;
    __syncthreads();
    s = (reds[0] + reds[1]) + (reds[2] + reds[3]);
    float inv = 1.0f / s;
    f16x8 o;
#pragma unroll
    for (int i = 0; i < 8; ++i) o[i] = (h16)(e[i] * inv);
    *(f16x8*)sr = o;
}

// ============ paired attention GEMM (r8 core; SMALL path only) ========
__global__ __launch_bounds__(256) void k_attn_pair(const h16* __restrict__ QKg,
                                                   float* __restrict__ Sbuf,
                                                   const h16* __restrict__ Pbuf,
                                                   const h16* __restrict__ Vtg,
                                                   float* __restrict__ Og,
                                                   int nS) {
    extern __shared__ char smem[];
    int bid = blockIdx.x;
    const int cpx = gridDim.x >> 3;
    bid = (bid & 7) * cpx + (bid >> 3);

    const int t = threadIdx.x;
    const int lane = t & 63, wave = t >> 6;
    const int wr = wave >> 1, wc = wave & 1;
    const int fr = lane & 15, kq = lane >> 4, fj = (lane >> 4) * 4;
    const int sw = fr & 7;
    const int loff = (((t & 7) ^ ((t >> 3) & 7)) * 8);

    const h16 *A, *Bt;
    float* C;
    int K, lda, ldb, ldc, rowBase, colBase;
    if (bid < nS) {
        int sb = bid >> 8, tile = bid & 255;
        rowBase = (tile >> 4) * 128; colBase = (tile & 15) * 128;
        A   = QKg + (size_t)sb * 4194304;
        Bt  = A + 2097152;
        C   = Sbuf + (size_t)sb * 4194304;
        K = 1024; lda = 1024; ldb = 1024; ldc = 2048;
    } else {
        int ob = bid - nS;
        int sb = ob >> 7, tile = ob & 127;
        rowBase = (tile >> 3) * 128; colBase = (tile & 7) * 128;
        A   = Pbuf + (size_t)sb * 4194304;
        Bt  = Vtg + (size_t)sb * 2097152;
        C   = Og + (size_t)sb * 2097152;
        K = 2048; lda = 2048; ldb = 2048; ldc = 1024;
    }

    const h16* Asrc = A + (size_t)(rowBase + (t >> 3)) * lda + loff;
    const h16* Bsrc = Bt + (size_t)(colBase + (t >> 3)) * ldb + loff;
    const size_t a32 = (size_t)32 * lda, b32 = (size_t)32 * ldb;

#define STG2(BUF, KT) do {                                                    \
        char* _ba = smem + (BUF) * 32768 + t * 16;                            \
        char* _bb = _ba + 16384;                                              \
        GLD16(Asrc + (KT), _ba);                                              \
        GLD16(Asrc + (KT) + a32, _ba + 4096);                                 \
        GLD16(Asrc + (KT) + 2 * a32, _ba + 8192);                             \
        GLD16(Asrc + (KT) + 3 * a32, _ba + 12288);                            \
        GLD16(Bsrc + (KT), _bb);                                              \
        GLD16(Bsrc + (KT) + b32, _bb + 4096);                                 \
        GLD16(Bsrc + (KT) + 2 * b32, _bb + 8192);                             \
        GLD16(Bsrc + (KT) + 3 * b32, _bb + 12288);                            \
    } while (0)

    f32x4 acc[4][4];
#pragma unroll
    for (int m = 0; m < 4; ++m)
#pragma unroll
        for (int n = 0; n < 4; ++n) acc[m][n] = (f32x4){0.f, 0.f, 0.f, 0.f};

#define RDF(BASE, R, S) \
    (*(const f16x8*)(smem + (BASE) + (R) * 128 + (((S) ^ sw) << 4)))

#define MFMA_BUF(BUF) do {                                                    \
        f16x8 af[4][2], bf[4][2];                                             \
        _Pragma("unroll") for (int m = 0; m < 4; ++m)                         \
        _Pragma("unroll") for (int ks = 0; ks < 2; ++ks)                      \
            af[m][ks] = RDF((BUF) * 32768,                                    \
                            wr * 64 + m * 16 + fr, kq + ks * 4);              \
        _Pragma("unroll") for (int n = 0; n < 4; ++n)                         \
        _Pragma("unroll") for (int ks = 0; ks < 2; ++ks)                      \
            bf[n][ks] = RDF((BUF) * 32768 + 16384,                            \
                            wc * 64 + n * 16 + fr, kq + ks * 4);              \
        _Pragma("unroll") for (int m = 0; m < 4; ++m)                         \
        _Pragma("unroll") for (int n = 0; n < 4; ++n)                         \
        _Pragma("unroll") for (int ks = 0; ks < 2; ++ks)                      \
            acc[m][n] = __builtin_amdgcn_mfma_f32_16x16x32_f16(               \
                af[m][ks], bf[n][ks], acc[m][n], 0, 0, 0);                    \
    } while (0)

    STG2(0, 0);
    __syncthreads();
    int cur = 0;
    for (int kt = 64; kt < K; kt += 64) {
        STG2(cur ^ 1, kt);
        MFMA_BUF(cur);
        __syncthreads();
        cur ^= 1;
    }
    MFMA_BUF(cur);

#pragma unroll
    for (int m = 0; m < 4; ++m)
#pragma unroll
        for (int n = 0; n < 4; ++n) {
            int cc = colBase + wc * 64 + n * 16 + fr;
#pragma unroll
            for (int j = 0; j < 4; ++j) {
                int rr = rowBase + wr * 64 + m * 16 + fj + j;
                C[(size_t)rr * ldc + cc] = acc[m][n][j];
            }
        }
#undef STG2
#undef RDF
#undef MFMA_BUF
}

// ---------------- r10 fallback softmax: S fp32 -> P fp16 ----------------
__global__ __launch_bounds__(256) void k_softmax(const float* __restrict__ S,
                                                 h16* __restrict__ P) {
    int row = blockIdx.x, t = threadIdx.x;
    const float* sr = S + (size_t)row * 2048 + t * 8;
    f32x4 a = *(const f32x4*)sr;
    f32x4 b = *(const f32x4*)(sr + 4);
    float m = fmaxf(fmaxf(fmaxf(a[0], a[1]), fmaxf(a[2], a[3])),
                    fmaxf(fmaxf(b[0], b[1]), fmaxf(b[2], b[3])));
#pragma unroll
    for (int off = 32; off; off >>= 1) m = fmaxf(m, __shfl_xor(m, off));
    __shared__ float redm[4], reds[4];
    if ((t & 63) == 0) redm[t >> 6] = m;
    __syncthreads();
    m = fmaxf(fmaxf(redm[0], redm[1]), fmaxf(redm[2], redm[3]));

    float e[8];
    e[0] = __expf(a[0] - m); e[1] = __expf(a[1] - m);
    e[2] = __expf(a[2] - m); e[3] = __expf(a[3] - m);
    e[4] = __expf(b[0] - m); e[5] = __expf(b[1] - m);
    e[6] = __expf(b[2] - m); e[7] = __expf(b[3] - m);
    float s = ((e[0] + e[1]) + (e[2] + e[3])) + ((e[4] + e[5]) + (e[6] + e[7]));
#pragma unroll
    for (int off = 32; off; off >>= 1) s += __shfl_xor(s, off);
    if ((t & 63) == 0) reds[t >> 6] = s;
    __syncthreads();
    s = (reds[0] + reds[1]) + (reds[2] + reds[3]);
    float inv = 1.0f / s;
    f16x8 o;
#pragma unroll
    for (int i = 0; i < 8; ++i) o[i] = (h16)(e[i] * inv);
    *(f16x8*)(P + (size_t)row * 2048 + t * 8) = o;
}

extern "C" void kernel_launch(void* const* d_in, const int* in_sizes, int n_in,
                              void* d_out, int out_size, void* d_ws, size_t ws_size,
                              hipStream_t stream) {
    (void)in_sizes; (void)n_in; (void)out_size;
    const float* X  = (const float*)d_in[0];
    const float* Wq = (const float*)d_in[1];
    const float* Wk = (const float*)d_in[2];
    const float* Wv = (const float*)d_in[3];

    char* ws = (char*)d_ws;
    h16*   Xh = (h16*)ws;
    h16*   Wt = (h16*)(ws + 33554432);
    h16*   Vt = (h16*)(ws + 39845888);
    h16*   QK = (h16*)d_out;
    float* O  = (float*)d_out;

    hipFuncSetAttribute((const void*)k_gemm_qkv256,
                        hipFuncAttributeMaxDynamicSharedMemorySize, 131072);
    hipFuncSetAttribute((const void*)k_sgemm256,
                        hipFuncAttributeMaxDynamicSharedMemorySize, 131072);
    hipFuncSetAttribute((const void*)k_ogemm256,
                        hipFuncAttributeMaxDynamicSharedMemorySize, 131072);
    hipFuncSetAttribute((const void*)k_attn_pair,
                        hipFuncAttributeMaxDynamicSharedMemorySize, 65536);

    k_conv<<<8960, 256, 0, stream>>>(X, Xh, Wq, Wk, Wv, Wt);
    k_gemm_qkv256<<<768, 512, 131072, stream>>>(Xh, Wt, QK, Vt);

    if (ws_size >= 144703488u) {
        // ---- BIG path: flat chain, fp16 seg-max S ----
        h16*   S16  = (h16*)(ws + 73400320);
        float* Smax = (float*)(ws + 140509184);
        k_sgemm256<<<512, 512, 131072, stream>>>(QK, S16, Smax);
        k_softmax16<<<16384, 256, 0, stream>>>(S16, Smax);
        k_ogemm256<<<256, 512, 131072, stream>>>(S16, Vt, O);
    } else {
        // ---- SMALL path: r10 chain ----
        float* S = (float*)ws;
        h16*   P = (h16*)(ws + 73400320);
        const size_t QKstride = 2 * 4194304;
        const size_t Vstride  = 2 * 2097152;
        k_attn_pair<<<512, 256, 65536, stream>>>(QK, S, P, Vt, O, 512);
        k_softmax<<<4096, 256, 0, stream>>>(S, P);
        for (int g = 1; g < 4; ++g) {
            k_attn_pair<<<768, 256, 65536, stream>>>(
                QK + (size_t)g * QKstride, S,
                P, Vt + (size_t)(g - 1) * Vstride, O + (size_t)(g - 1) * Vstride, 512);
            k_softmax<<<4096, 256, 0, stream>>>(S, P);
        }
        k_attn_pair<<<256, 256, 65536, stream>>>(
            QK, S, P, Vt + 3 * Vstride, O + 3 * Vstride, 0);
    }
}

// Round 15
// 288.372 us; speedup vs baseline: 8.6233x; 1.0243x over previous
//
#include <hip/hip_runtime.h>
#include <stdint.h>

typedef _Float16 h16;
typedef __attribute__((ext_vector_type(8))) _Float16 f16x8;
typedef __attribute__((ext_vector_type(4))) float f32x4;

// Problem: B=8, T=2048, D=1024, NODES=1024  (fp32 in/out)
//
// Shared ws prefix (both paths):
//   Xh  @ 0         : 33554432   (X fp16)            -- dead after qkv
//   Wt  @ 33554432  : 6291456    (W^T fp16 [n][d])   -- dead after qkv
//   Vt  @ 39845888  : 33554432   (V^T fp16 [b][n][t])-- live to end
// BIG path (ws >= 144703488): flat chain, S stored fp16 relative to seg-max:
//   S16 @ 73400320  : 67108864   ([b][row][2048] h16 = s - m_seg; P in-place)
//   Smax@ 140509184 : 4194304    ([b][row][64] f32 per-32col-seg max)
//   chain: conv, qkv256, S_all(512), SM_all(16384), O_all(256)
// GEMM core: 256x256 8-phase, BK=64, 128 KiB LDS + B-HOLD regs (r15):
//   b[2][2][2] keeps both nh-bands of B across mh phases -> LDS reads
//   32->24 KB per wave-K-tile (core was LDS-read-BW bound at 41% MfmaUtil).
// SMALL path (r10 fallback): group-of-2 pairing chain.
// Q,K fp16 live in d_out per-batch [Q_b|K_b] 8 MiB; O_b fp32 overwrites it.

#define GLD16(gsrc, ldst)                                                     \
    __builtin_amdgcn_global_load_lds(                                         \
        (const __attribute__((address_space(1))) uint32_t*)(gsrc),            \
        (__attribute__((address_space(3))) uint32_t*)(ldst), 16, 0, 0)

#define FENCE asm volatile("" ::: "memory")
#define BARRIER do { FENCE; __builtin_amdgcn_s_barrier(); FENCE; } while (0)
#define LGKM0  asm volatile("s_waitcnt lgkmcnt(0)" ::: "memory")
#define VMCNT4 asm volatile("s_waitcnt vmcnt(4)" ::: "memory")
#define VMCNT0 asm volatile("s_waitcnt vmcnt(0)" ::: "memory")

// ---------------- merged conversion kernel ----------------
__global__ __launch_bounds__(256) void k_conv(const float* __restrict__ X,
                                              h16* __restrict__ Xh,
                                              const float* __restrict__ W0,
                                              const float* __restrict__ W1,
                                              const float* __restrict__ W2,
                                              h16* __restrict__ Wt) {
    __shared__ h16 LT[64 * 72];
    int t = threadIdx.x;
    if (blockIdx.x < 8192) {
        size_t i = ((size_t)blockIdx.x * 256 + t) * 8;
        f32x4 a = *(const f32x4*)(X + i);
        f32x4 b = *(const f32x4*)(X + i + 4);
        f16x8 o;
        o[0] = (h16)a[0]; o[1] = (h16)a[1]; o[2] = (h16)a[2]; o[3] = (h16)a[3];
        o[4] = (h16)b[0]; o[5] = (h16)b[1]; o[6] = (h16)b[2]; o[7] = (h16)b[3];
        *(f16x8*)(Xh + i) = o;
        return;
    }
    int bid2 = blockIdx.x - 8192;
    int which = bid2 >> 8;
    int tile  = bid2 & 255;
    int d0 = (tile >> 4) * 64, n0 = (tile & 15) * 64;
    const float* W = (which == 0) ? W0 : ((which == 1) ? W1 : W2);
    h16* dst = Wt + (size_t)which * (1024 * 1024);
#pragma unroll
    for (int p = 0; p < 4; ++p) {
        int c = t + p * 256;
        int r = c >> 4;
        int cf = (c & 15) * 4;
        f32x4 v = *(const f32x4*)&W[(size_t)(d0 + r) * 1024 + n0 + cf];
#pragma unroll
        for (int e = 0; e < 4; ++e) LT[(cf + e) * 72 + r] = (h16)v[e];
    }
    __syncthreads();
#pragma unroll
    for (int p = 0; p < 2; ++p) {
        int q = t + p * 256;
        int nl = q >> 3;
        int dc = (q & 7) * 8;
        f16x8 v = *(f16x8*)&LT[nl * 72 + dc];
        *(f16x8*)&dst[(size_t)(n0 + nl) * 1024 + d0 + dc] = v;
    }
}

// ===== shared 256x256 8-phase core macros (BK=64, 128 KiB LDS, B-hold) =====
// Require locals: smem, t, loff, sw, A, Bt, rowBase, nc0, wr, wc, fr, kq,
//                 acc, a, b, and compile-time-const size_t ldab (row stride).
#define STAGE_OP(OPREG, OPPTR, OPROW, BUF, H, KT) do {                          \
        const h16* _src = (OPPTR) + (size_t)((OPROW) + (H) * 128 + (t >> 3)) * ldab \
                          + (KT) * 64 + loff;                                   \
        char* _dst = smem + (OPREG) + (BUF) * 32768 + (H) * 16384 + t * 16;     \
        GLD16(_src, _dst);                                                      \
        GLD16(_src + 64 * ldab, _dst + 8192);                                   \
    } while (0)
#define STAGE_A(BUF, H, KT) STAGE_OP(0, A, rowBase, BUF, H, KT)
#define STAGE_B(BUF, H, KT) STAGE_OP(65536, Bt, nc0, BUF, H, KT)

#define RD(REG, ROW, SLOT) \
    (*(const f16x8*)(smem + (REG) + (ROW) * 128 + ((((SLOT)) ^ sw) << 4)))

// DOA: (re)load A-quadrant for MH.  DOB: (re)load B-band for NH into b[NH].
// B is held in registers across the two MH phases (reads 32->24 KB/K-tile).
#define PH(BUF, MH, NH, DOA, DOB, STG, VM) do {                                 \
        if (DOA) {                                                              \
            _Pragma("unroll") for (int q = 0; q < 4; ++q)                       \
            _Pragma("unroll") for (int ks = 0; ks < 2; ++ks)                    \
                a[q][ks] = RD((BUF) * 32768,                                    \
                              (MH) * 128 + wr * 64 + q * 16 + fr, kq + ks * 4); \
        }                                                                       \
        if (DOB) {                                                              \
            _Pragma("unroll") for (int nf = 0; nf < 2; ++nf)                    \
            _Pragma("unroll") for (int ks = 0; ks < 2; ++ks)                    \
                b[NH][nf][ks] = RD(65536 + (BUF) * 32768,                       \
                           (NH) * 128 + wc * 32 + nf * 16 + fr, kq + ks * 4);   \
        }                                                                       \
        STG;                                                                    \
        VM;                                                                     \
        BARRIER; LGKM0;                                                         \
        __builtin_amdgcn_s_setprio(1);                                          \
        _Pragma("unroll") for (int q = 0; q < 4; ++q)                           \
        _Pragma("unroll") for (int nf = 0; nf < 2; ++nf)                        \
        _Pragma("unroll") for (int ks = 0; ks < 2; ++ks)                        \
            acc[MH][NH][q][nf] = __builtin_amdgcn_mfma_f32_16x16x32_f16(        \
                a[q][ks], b[NH][nf][ks], acc[MH][NH][q][nf], 0, 0, 0);          \
        __builtin_amdgcn_s_setprio(0);                                          \
        BARRIER;                                                                \
    } while (0)

// NTT = number of 64-wide K-tiles (power of 2). Wrap staging via &(NTT-1).
#define CORE_LOOP(NTT)                                                          \
    STAGE_A(0, 0, 0); STAGE_A(0, 1, 0);                                         \
    STAGE_B(0, 0, 0); STAGE_B(0, 1, 0);                                         \
    STAGE_A(1, 0, 1); STAGE_B(1, 0, 1);                                         \
    VMCNT4;                                                                     \
    BARRIER;                                                                    \
    for (int i = 0; i < (NTT) / 2; ++i) {                                       \
        const int tb  = 2 * i + 1;                                              \
        const int tc2 = (2 * i + 2) & ((NTT) - 1);                              \
        const int td  = (2 * i + 3) & ((NTT) - 1);                              \
        PH(0, 0, 0, 1, 1, STAGE_A(1, 1, tb),  (void)0);                         \
        PH(0, 0, 1, 0, 1, STAGE_B(1, 1, tb),  (void)0);                         \
        PH(0, 1, 0, 1, 0, STAGE_A(0, 0, tc2), (void)0);                         \
        PH(0, 1, 1, 0, 0, STAGE_B(0, 0, tc2), VMCNT4);                          \
        PH(1, 0, 0, 1, 1, STAGE_A(0, 1, tc2), (void)0);                         \
        PH(1, 0, 1, 0, 1, STAGE_B(0, 1, tc2), (void)0);                         \
        PH(1, 1, 0, 1, 0, STAGE_A(1, 0, td),  (void)0);                         \
        PH(1, 1, 1, 0, 0, STAGE_B(1, 0, td),  VMCNT4);                          \
    }                                                                           \
    VMCNT0;                                                                     \
    BARRIER;

// ============ 256x256 8-phase QKV GEMM ============
__global__ __launch_bounds__(512, 2) void k_gemm_qkv256(const h16* __restrict__ Xh,
                                                        const h16* __restrict__ Wt,
                                                        h16* __restrict__ qk,
                                                        h16* __restrict__ vt) {
    extern __shared__ char smem[];
    const int t = threadIdx.x;
    const int lane = t & 63, wave = t >> 6;
    const int wr = wave >> 2, wc = wave & 3;
    const int fr = lane & 15, kq = lane >> 4;
    const int sw = fr & 7;
    const int loff = (((t & 7) ^ ((t >> 3) & 7)) * 8);
    const size_t ldab = 1024;

    int bid = blockIdx.x;
    bid = (bid & 7) * 96 + (bid >> 3);        // XCD swizzle (768 % 8 == 0)
    const int nt = bid % 12, mt = bid / 12;
    const int rowBase = mt * 256;
    const int colBaseF = nt * 256;
    const int which = nt >> 2;
    const int nc0 = colBaseF & 1023;
    const h16* A  = Xh;
    const h16* Bt = Wt + (size_t)which * (1024 * 1024);

    f32x4 acc[2][2][4][2];
#pragma unroll
    for (int mh = 0; mh < 2; ++mh)
#pragma unroll
        for (int nh = 0; nh < 2; ++nh)
#pragma unroll
            for (int q = 0; q < 4; ++q)
#pragma unroll
                for (int nf = 0; nf < 2; ++nf)
                    acc[mh][nh][q][nf] = (f32x4){0.f, 0.f, 0.f, 0.f};
    f16x8 a[4][2], b[2][2][2];

    CORE_LOOP(16)

    const int bat  = rowBase >> 11;
    const int tloc = rowBase & 2047;

    if (which < 2) {
        h16* dst = qk + (size_t)bat * 4194304 + (which == 1 ? 2097152u : 0u);
#pragma unroll
        for (int mh = 0; mh < 2; ++mh)
#pragma unroll
            for (int nh = 0; nh < 2; ++nh)
#pragma unroll
                for (int q = 0; q < 4; ++q)
#pragma unroll
                    for (int nf = 0; nf < 2; ++nf) {
                        int cc = nc0 + nh * 128 + wc * 32 + nf * 16 + fr;
#pragma unroll
                        for (int j = 0; j < 4; ++j) {
                            int rr = tloc + mh * 128 + wr * 64 + q * 16 + kq * 4 + j;
                            dst[(size_t)rr * 1024 + cc] = (h16)acc[mh][nh][q][nf][j];
                        }
                    }
    } else {
        h16* LT = (h16*)smem;  // [256 n][136 t-pad]
        const size_t bvt = (size_t)bat * 2097152;
#pragma unroll
        for (int mh = 0; mh < 2; ++mh) {
            __syncthreads();
#pragma unroll
            for (int nh = 0; nh < 2; ++nh)
#pragma unroll
                for (int q = 0; q < 4; ++q)
#pragma unroll
                    for (int nf = 0; nf < 2; ++nf) {
                        int cl = nh * 128 + wc * 32 + nf * 16 + fr;
#pragma unroll
                        for (int j = 0; j < 4; ++j) {
                            int rl = wr * 64 + q * 16 + kq * 4 + j;
                            LT[cl * 136 + rl] = (h16)acc[mh][nh][q][nf][j];
                        }
                    }
            __syncthreads();
#pragma unroll
            for (int p = 0; p < 8; ++p) {
                int idx = t + p * 512;
                int nl = idx >> 4;
                int tc = (idx & 15) * 8;
                *(f16x8*)&vt[bvt + (size_t)(nc0 + nl) * 2048 + tloc + mh * 128 + tc] =
                    *(f16x8*)&LT[nl * 136 + tc];
            }
        }
    }
}

// ============ S_all: 256x256 8-phase, S16 = s - segmax epilogue (BIG path) ==========
__global__ __launch_bounds__(512, 2) void k_sgemm256(const h16* __restrict__ qkin,
                                                     h16* __restrict__ s16,
                                                     float* __restrict__ smax) {
    extern __shared__ char smem[];
    const int t = threadIdx.x;
    const int lane = t & 63, wave = t >> 6;
    const int wr = wave >> 2, wc = wave & 3;
    const int fr = lane & 15, kq = lane >> 4;
    const int sw = fr & 7;
    const int loff = (((t & 7) ^ ((t >> 3) & 7)) * 8);
    const size_t ldab = 1024;

    int bid = blockIdx.x;
    bid = (bid & 7) * 64 + (bid >> 3);        // XCD swizzle (512 % 8 == 0)
    const int sb = bid >> 6;
    const int tile = bid & 63;
    const int rowBase = (tile >> 3) * 256;
    const int nc0 = (tile & 7) * 256;
    const h16* A  = qkin + (size_t)sb * 4194304;   // Q_b  [2048 x 1024]
    const h16* Bt = A + 2097152;                   // K_b  [2048 x 1024]

    f32x4 acc[2][2][4][2];
#pragma unroll
    for (int mh = 0; mh < 2; ++mh)
#pragma unroll
        for (int nh = 0; nh < 2; ++nh)
#pragma unroll
            for (int q = 0; q < 4; ++q)
#pragma unroll
                for (int nf = 0; nf < 2; ++nf)
                    acc[mh][nh][q][nf] = (f32x4){0.f, 0.f, 0.f, 0.f};
    f16x8 a[4][2], b[2][2][2];

    CORE_LOOP(16)

    h16*   srow = s16 + (size_t)sb * 4194304;      // [2048][2048] h16
    float* smx  = smax + (size_t)sb * 131072;      // [2048][64]   f32
#pragma unroll
    for (int mh = 0; mh < 2; ++mh)
#pragma unroll
        for (int nh = 0; nh < 2; ++nh) {
            const int segIdx = (nc0 >> 5) + nh * 4 + wc;
#pragma unroll
            for (int q = 0; q < 4; ++q)
#pragma unroll
                for (int j = 0; j < 4; ++j) {
                    float mx = fmaxf(acc[mh][nh][q][0][j], acc[mh][nh][q][1][j]);
                    mx = fmaxf(mx, __shfl_xor(mx, 1));
                    mx = fmaxf(mx, __shfl_xor(mx, 2));
                    mx = fmaxf(mx, __shfl_xor(mx, 4));
                    mx = fmaxf(mx, __shfl_xor(mx, 8));
                    int rr = rowBase + mh * 128 + wr * 64 + q * 16 + kq * 4 + j;
#pragma unroll
                    for (int nf = 0; nf < 2; ++nf) {
                        int cc = nc0 + nh * 128 + wc * 32 + nf * 16 + fr;
                        srow[(size_t)rr * 2048 + cc] = (h16)(acc[mh][nh][q][nf][j] - mx);
                    }
                    if (fr == 0) smx[rr * 64 + segIdx] = mx;
                }
        }
}

// ============ O_all: 256x256 8-phase, K=2048, P(fp16 in S16) @ Vt^T (BIG path) ======
__global__ __launch_bounds__(512, 2) void k_ogemm256(const h16* __restrict__ p16,
                                                     const h16* __restrict__ vt,
                                                     float* __restrict__ Oall) {
    extern __shared__ char smem[];
    const int t = threadIdx.x;
    const int lane = t & 63, wave = t >> 6;
    const int wr = wave >> 2, wc = wave & 3;
    const int fr = lane & 15, kq = lane >> 4;
    const int sw = fr & 7;
    const int loff = (((t & 7) ^ ((t >> 3) & 7)) * 8);
    const size_t ldab = 2048;

    int bid = blockIdx.x;
    bid = (bid & 7) * 32 + (bid >> 3);        // XCD swizzle (256 % 8 == 0)
    const int sb = bid >> 5;                  // batch
    const int tile = bid & 31;                // 8 mt x 4 nt
    const int rowBase = (tile >> 2) * 256;
    const int nc0 = (tile & 3) * 256;
    const h16* A  = p16 + (size_t)sb * 4194304;   // P_b  [2048 x 2048]
    const h16* Bt = vt + (size_t)sb * 2097152;    // Vt_b [1024 x 2048]

    f32x4 acc[2][2][4][2];
#pragma unroll
    for (int mh = 0; mh < 2; ++mh)
#pragma unroll
        for (int nh = 0; nh < 2; ++nh)
#pragma unroll
            for (int q = 0; q < 4; ++q)
#pragma unroll
                for (int nf = 0; nf < 2; ++nf)
                    acc[mh][nh][q][nf] = (f32x4){0.f, 0.f, 0.f, 0.f};
    f16x8 a[4][2], b[2][2][2];

    CORE_LOOP(32)

    float* Ob = Oall + (size_t)sb * 2097152;
#pragma unroll
    for (int mh = 0; mh < 2; ++mh)
#pragma unroll
        for (int nh = 0; nh < 2; ++nh)
#pragma unroll
            for (int q = 0; q < 4; ++q)
#pragma unroll
                for (int nf = 0; nf < 2; ++nf) {
                    int cc = nc0 + nh * 128 + wc * 32 + nf * 16 + fr;
#pragma unroll
                    for (int j = 0; j < 4; ++j) {
                        int rr = rowBase + mh * 128 + wr * 64 + q * 16 + kq * 4 + j;
                        Ob[(size_t)rr * 1024 + cc] = acc[mh][nh][q][nf][j];
                    }
                }
}

// ============ SM_all: softmax over s16 (+segmax), P written in place (BIG path) =====
__global__ __launch_bounds__(256) void k_softmax16(h16* __restrict__ s16,
                                                   const float* __restrict__ smax) {
    int row = blockIdx.x, t = threadIdx.x;
    const float* smx = smax + (size_t)row * 64;
    float m = smx[t & 63];
#pragma unroll
    for (int off = 32; off; off >>= 1) m = fmaxf(m, __shfl_xor(m, off));

    h16* sr = s16 + (size_t)row * 2048 + t * 8;
    f16x8 v = *(f16x8*)sr;
    float msg = smx[t >> 2] - m;
    float e[8];
#pragma unroll
    for (int i = 0; i < 8; ++i) e[i] = __expf((float)v[i] + msg);
    float s = ((e[0] + e[1]) + (e[2] + e[3])) + ((e[4] + e[5]) + (e[6] + e[7]));
#pragma unroll
    for (int off = 32; off; off >>= 1) s += __shfl_xor(s, off);
    __shared__ float reds[4];
    if ((t & 63) == 0) reds[t >> 6] = s;
    __syncthreads();
    s = (reds[0] + reds[1]) + (reds[2] + reds[3]);
    float inv = 1.0f / s;
    f16x8 o;
#pragma unroll
    for (int i = 0; i < 8; ++i) o[i] = (h16)(e[i] * inv);
    *(f16x8*)sr = o;
}

// ============ paired attention GEMM (r8 core; SMALL path only) ========
__global__ __launch_bounds__(256) void k_attn_pair(const h16* __restrict__ QKg,
                                                   float* __restrict__ Sbuf,
                                                   const h16* __restrict__ Pbuf,
                                                   const h16* __restrict__ Vtg,
                                                   float* __restrict__ Og,
                                                   int nS) {
    extern __shared__ char smem[];
    int bid = blockIdx.x;
    const int cpx = gridDim.x >> 3;
    bid = (bid & 7) * cpx + (bid >> 3);

    const int t = threadIdx.x;
    const int lane = t & 63, wave = t >> 6;
    const int wr = wave >> 1, wc = wave & 1;
    const int fr = lane & 15, kq = lane >> 4, fj = (lane >> 4) * 4;
    const int sw = fr & 7;
    const int loff = (((t & 7) ^ ((t >> 3) & 7)) * 8);

    const h16 *A, *Bt;
    float* C;
    int K, lda, ldb, ldc, rowBase, colBase;
    if (bid < nS) {
        int sb = bid >> 8, tile = bid & 255;
        rowBase = (tile >> 4) * 128; colBase = (tile & 15) * 128;
        A   = QKg + (size_t)sb * 4194304;
        Bt  = A + 2097152;
        C   = Sbuf + (size_t)sb * 4194304;
        K = 1024; lda = 1024; ldb = 1024; ldc = 2048;
    } else {
        int ob = bid - nS;
        int sb = ob >> 7, tile = ob & 127;
        rowBase = (tile >> 3) * 128; colBase = (tile & 7) * 128;
        A   = Pbuf + (size_t)sb * 4194304;
        Bt  = Vtg + (size_t)sb * 2097152;
        C   = Og + (size_t)sb * 2097152;
        K = 2048; lda = 2048; ldb = 2048; ldc = 1024;
    }

    const h16* Asrc = A + (size_t)(rowBase + (t >> 3)) * lda + loff;
    const h16* Bsrc = Bt + (size_t)(colBase + (t >> 3)) * ldb + loff;
    const size_t a32 = (size_t)32 * lda, b32 = (size_t)32 * ldb;

#define STG2(BUF, KT) do {                                                    \
        char* _ba = smem + (BUF) * 32768 + t * 16;                            \
        char* _bb = _ba + 16384;                                              \
        GLD16(Asrc + (KT), _ba);                                              \
        GLD16(Asrc + (KT) + a32, _ba + 4096);                                 \
        GLD16(Asrc + (KT) + 2 * a32, _ba + 8192);                             \
        GLD16(Asrc + (KT) + 3 * a32, _ba + 12288);                            \
        GLD16(Bsrc + (KT), _bb);                                              \
        GLD16(Bsrc + (KT) + b32, _bb + 4096);                                 \
        GLD16(Bsrc + (KT) + 2 * b32, _bb + 8192);                             \
        GLD16(Bsrc + (KT) + 3 * b32, _bb + 12288);                            \
    } while (0)

    f32x4 acc[4][4];
#pragma unroll
    for (int m = 0; m < 4; ++m)
#pragma unroll
        for (int n = 0; n < 4; ++n) acc[m][n] = (f32x4){0.f, 0.f, 0.f, 0.f};

#define RDF(BASE, R, S) \
    (*(const f16x8*)(smem + (BASE) + (R) * 128 + (((S) ^ sw) << 4)))

#define MFMA_BUF(BUF) do {                                                    \
        f16x8 af[4][2], bf[4][2];                                             \
        _Pragma("unroll") for (int m = 0; m < 4; ++m)                         \
        _Pragma("unroll") for (int ks = 0; ks < 2; ++ks)                      \
            af[m][ks] = RDF((BUF) * 32768,                                    \
                            wr * 64 + m * 16 + fr, kq + ks * 4);              \
        _Pragma("unroll") for (int n = 0; n < 4; ++n)                         \
        _Pragma("unroll") for (int ks = 0; ks < 2; ++ks)                      \
            bf[n][ks] = RDF((BUF) * 32768 + 16384,                            \
                            wc * 64 + n * 16 + fr, kq + ks * 4);              \
        _Pragma("unroll") for (int m = 0; m < 4; ++m)                         \
        _Pragma("unroll") for (int n = 0; n < 4; ++n)                         \
        _Pragma("unroll") for (int ks = 0; ks < 2; ++ks)                      \
            acc[m][n] = __builtin_amdgcn_mfma_f32_16x16x32_f16(               \
                af[m][ks], bf[n][ks], acc[m][n], 0, 0, 0);                    \
    } while (0)

    STG2(0, 0);
    __syncthreads();
    int cur = 0;
    for (int kt = 64; kt < K; kt += 64) {
        STG2(cur ^ 1, kt);
        MFMA_BUF(cur);
        __syncthreads();
        cur ^= 1;
    }
    MFMA_BUF(cur);

#pragma unroll
    for (int m = 0; m < 4; ++m)
#pragma unroll
        for (int n = 0; n < 4; ++n) {
            int cc = colBase + wc * 64 + n * 16 + fr;
#pragma unroll
            for (int j = 0; j < 4; ++j) {
                int rr = rowBase + wr * 64 + m * 16 + fj + j;
                C[(size_t)rr * ldc + cc] = acc[m][n][j];
            }
        }
#undef STG2
#undef RDF
#undef MFMA_BUF
}

// ---------------- r10 fallback softmax: S fp32 -> P fp16 ----------------
__global__ __launch_bounds__(256) void k_softmax(const float* __restrict__ S,
                                                 h16* __restrict__ P) {
    int row = blockIdx.x, t = threadIdx.x;
    const float* sr = S + (size_t)row * 2048 + t * 8;
    f32x4 a = *(const f32x4*)sr;
    f32x4 b = *(const f32x4*)(sr + 4);
    float m = fmaxf(fmaxf(fmaxf(a[0], a[1]), fmaxf(a[2], a[3])),
                    fmaxf(fmaxf(b[0], b[1]), fmaxf(b[2], b[3])));
#pragma unroll
    for (int off = 32; off; off >>= 1) m = fmaxf(m, __shfl_xor(m, off));
    __shared__ float redm[4], reds[4];
    if ((t & 63) == 0) redm[t >> 6] = m;
    __syncthreads();
    m = fmaxf(fmaxf(redm[0], redm[1]), fmaxf(redm[2], redm[3]));

    float e[8];
    e[0] = __expf(a[0] - m); e[1] = __expf(a[1] - m);
    e[2] = __expf(a[2] - m); e[3] = __expf(a[3] - m);
    e[4] = __expf(b[0] - m); e[5] = __expf(b[1] - m);
    e[6] = __expf(b[2] - m); e[7] = __expf(b[3] - m);
    float s = ((e[0] + e[1]) + (e[2] + e[3])) + ((e[4] + e[5]) + (e[6] + e[7]));
#pragma unroll
    for (int off = 32; off; off >>= 1) s += __shfl_xor(s, off);
    if ((t & 63) == 0) reds[t >> 6] = s;
    __syncthreads();
    s = (reds[0] + reds[1]) + (reds[2] + reds[3]);
    float inv = 1.0f / s;
    f16x8 o;
#pragma unroll
    for (int i = 0; i < 8; ++i) o[i] = (h16)(e[i] * inv);
    *(f16x8*)(P + (size_t)row * 2048 + t * 8) = o;
}

extern "C" void kernel_launch(void* const* d_in, const int* in_sizes, int n_in,
                              void* d_out, int out_size, void* d_ws, size_t ws_size,
                              hipStream_t stream) {
    (void)in_sizes; (void)n_in; (void)out_size;
    const float* X  = (const float*)d_in[0];
    const float* Wq = (const float*)d_in[1];
    const float* Wk = (const float*)d_in[2];
    const float* Wv = (const float*)d_in[3];

    char* ws = (char*)d_ws;
    h16*   Xh = (h16*)ws;
    h16*   Wt = (h16*)(ws + 33554432);
    h16*   Vt = (h16*)(ws + 39845888);
    h16*   QK = (h16*)d_out;
    float* O  = (float*)d_out;

    hipFuncSetAttribute((const void*)k_gemm_qkv256,
                        hipFuncAttributeMaxDynamicSharedMemorySize, 131072);
    hipFuncSetAttribute((const void*)k_sgemm256,
                        hipFuncAttributeMaxDynamicSharedMemorySize, 131072);
    hipFuncSetAttribute((const void*)k_ogemm256,
                        hipFuncAttributeMaxDynamicSharedMemorySize, 131072);
    hipFuncSetAttribute((const void*)k_attn_pair,
                        hipFuncAttributeMaxDynamicSharedMemorySize, 65536);

    k_conv<<<8960, 256, 0, stream>>>(X, Xh, Wq, Wk, Wv, Wt);
    k_gemm_qkv256<<<768, 512, 131072, stream>>>(Xh, Wt, QK, Vt);

    if (ws_size >= 144703488u) {
        // ---- BIG path: flat chain, fp16 seg-max S ----
        h16*   S16  = (h16*)(ws + 73400320);
        float* Smax = (float*)(ws + 140509184);
        k_sgemm256<<<512, 512, 131072, stream>>>(QK, S16, Smax);
        k_softmax16<<<16384, 256, 0, stream>>>(S16, Smax);
        k_ogemm256<<<256, 512, 131072, stream>>>(S16, Vt, O);
    } else {
        // ---- SMALL path: r10 chain ----
        float* S = (float*)ws;
        h16*   P = (h16*)(ws + 73400320);
        const size_t QKstride = 2 * 4194304;
        const size_t Vstride  = 2 * 2097152;
        k_attn_pair<<<512, 256, 65536, stream>>>(QK, S, P, Vt, O, 512);
        k_softmax<<<4096, 256, 0, stream>>>(S, P);
        for (int g = 1; g < 4; ++g) {
            k_attn_pair<<<768, 256, 65536, stream>>>(
                QK + (size_t)g * QKstride, S,
                P, Vt + (size_t)(g - 1) * Vstride, O + (size_t)(g - 1) * Vstride, 512);
            k_softmax<<<4096, 256, 0, stream>>>(S, P);
        }
        k_attn_pair<<<256, 256, 65536, stream>>>(
            QK, S, P, Vt + 3 * Vstride, O + 3 * Vstride, 0);
    }
}